// Round 16
// baseline (321.407 us; speedup 1.0000x reference)
//
#include <hip/hip_runtime.h>
#include <hip/hip_bf16.h>
#include <math.h>

typedef __bf16 bf16x8 __attribute__((ext_vector_type(8)));
typedef float f32x4 __attribute__((ext_vector_type(4)));

constexpr int C_ = 128, HID_ = 512, T_ = 512, F_ = 128, B_ = 4;
constexpr int PIMG = T_ * F_;  // 65536 positions per image

// ---------------- Kernel 0: weight fp32 -> bf16 ----------------
__global__ void wcvt_k(const float* __restrict__ w1, const float* __restrict__ w2,
                       __bf16* __restrict__ w1b, __bf16* __restrict__ w2b) {
    int i = blockIdx.x * 256 + threadIdx.x;   // 65536 each
    w1b[i] = (__bf16)w1[i];
    w2b[i] = (__bf16)w2[i];
}

// ---------------- Kernel A: depthwise 7x7 conv, 16B-ALIGNED LDS tile ----------------
// KNOWN GOOD structure (round 6); templated output type. ~35 us.
template <typename OT>
__global__ __launch_bounds__(256) void dwconv_k(
    const float* __restrict__ x, const float* __restrict__ dww,
    const float* __restrict__ dwb, OT* __restrict__ y) {
    __shared__ float tile[38][140];  // rows t0-3..t0+34; 21280 B
    const int bx = blockIdx.x;
    const int tt = bx & 15, c = (bx >> 4) & 127, b = bx >> 11;
    const int t0 = tt * 32;
    const float* xp = x + ((size_t)(b * C_ + c)) * PIMG;

    float wr[49];  // uniform per block -> scalarized
#pragma unroll
    for (int i = 0; i < 49; ++i) wr[i] = dww[c * 49 + i];
    const float bias = dwb[c];

    const int colq = threadIdx.x & 31;
    const int rg = threadIdx.x >> 5;
    for (int r = rg; r < 38; r += 8) {
        const int t = t0 - 3 + r;
        f32x4 v = {0.f, 0.f, 0.f, 0.f};
        if (t >= 0 && t < T_) v = *(const f32x4*)(xp + (size_t)t * F_ + colq * 4);
        *(f32x4*)&tile[r][4 + colq * 4] = v;   // 16B-aligned
        if (colq == 0) { tile[r][1] = 0.f; tile[r][2] = 0.f; tile[r][3] = 0.f; }
        if (colq == 31) { tile[r][132] = 0.f; tile[r][133] = 0.f; tile[r][134] = 0.f; }
    }
    __syncthreads();

    const int f = threadIdx.x & 127;
    const int g = threadIdx.x >> 7;  // 0..1 -> 16 t-rows each
    float acc[16];
#pragma unroll
    for (int i = 0; i < 16; ++i) acc[i] = 0.f;
#pragma unroll
    for (int df = 0; df < 7; ++df) {
        float colv[22];  // sliding window: 22 loads feed 112 FMAs
#pragma unroll
        for (int j = 0; j < 22; ++j) colv[j] = tile[g * 16 + j][1 + f + df];
#pragma unroll
        for (int dr = 0; dr < 7; ++dr) {
            const float wv = wr[dr * 7 + df];
#pragma unroll
            for (int i = 0; i < 16; ++i) acc[i] += colv[i + dr] * wv;
        }
    }
    OT* yp = y + ((size_t)(b * C_ + c)) * PIMG + (size_t)(t0 + g * 16) * F_ + f;
#pragma unroll
    for (int i = 0; i < 16; ++i) yp[(size_t)i * F_] = (OT)(acc[i] + bias);
}

// gelu = 0.5x(1+tanh(u)) == x / (1 + exp(-2u))  [exact rewrite, validated r12-r15]
__device__ __forceinline__ float gelu_tanh(float xv) {
    const float u2 = 1.5957691216057308f * (xv + 0.044715f * xv * xv * xv);  // 2u
    const float e = __expf(-u2);
    return __fdividef(xv, 1.f + e);
}

// ---------------- Kernel B: 4-pass GEMM1 -> peak 80 regs -> 6 waves/SIMD ----------------
// grid: B * (PIMG/64) = 4096 blocks, 512 threads (8 waves).
// Unified-RF model (fits r12-r15 data): waves/SIMD = floor(512/(VGPR+AGPR)).
// r15 peaked at 48V+48A=96 -> 5 waves -> 2 blocks. This round: GEMM1 in 4 passes
// of 16 hid/wave (acc1=16 AGPR); ph7 peak = 16+16 AGPR + ~48 VGPR = 80 <= 85 ->
// 6 waves/SIMD -> 3 blocks/CU (LDS 3x51.2KB = 153.6 <= 160KB).
// Same hid row arithmetic, ascending k => outputs bit-identical to r15.
// Fallback (YT=float): y may alias out — disjoint regions, reads before writes.
template <typename YT>
__global__ __launch_bounds__(512, 6) void lnmlp_k(
    const YT* y,
    const __bf16* __restrict__ w1b, const __bf16* __restrict__ w2b,
    const float* __restrict__ lng, const float* __restrict__ lnb,
    const float* __restrict__ b1, const float* __restrict__ b2,
    const float* __restrict__ ls, float* out) {
    constexpr bool YBF = (sizeof(YT) == 2);
    constexpr int YB_BYTES = 17408;                       // yb [64][136] bf16
    constexpr int YRAW_BYTES = YBF ? 16384 : 34816;       // [128][64]bf16 | [128][68]f32
    constexpr int FRESH_OFF = YB_BYTES + YRAW_BYTES;      // statics region (6 KB)
    constexpr int CHUNK_END = YB_BYTES + 33792;           // hl [64][264] end
    constexpr int A_ = FRESH_OFF + 6144;
    constexpr int SMEM_SZ = (A_ > CHUNK_END) ? A_ : CHUNK_END;  // 51200 bf16 / 58368 f32
    __shared__ __align__(16) unsigned char smem[SMEM_SZ];
    unsigned short (*yb)[136] = (unsigned short (*)[136])smem;
    unsigned short (*yraw_b)[64] = (unsigned short (*)[64])(smem + YB_BYTES);
    float (*yraw_f)[68] = (float (*)[68])(smem + YB_BYTES);
    unsigned short (*hl)[264] = (unsigned short (*)[264])(smem + YB_BYTES);  // overlays yraw+statics
    float (*pls)[64] = (float (*)[64])(smem + FRESH_OFF);          // live ph2-3 only
    float (*pls2)[64] = (float (*)[64])(smem + FRESH_OFF + 2048);
    double* mud = (double*)(smem + FRESH_OFF + 4096);              // live ph3-4
    double* rsd = (double*)(smem + FRESH_OFF + 4608);
    float* lgs = (float*)(smem + FRESH_OFF + 5120);                // live ph0-4
    float* lbs = (float*)(smem + FRESH_OFF + 5632);

    const int tid = threadIdx.x;
    const int lane = tid & 63, wv = tid >> 6;
    const int b = blockIdx.x >> 10;
    const int p0 = (blockIdx.x & 1023) * 64;
    const YT* yp = y + (size_t)b * ((size_t)C_ * PIMG) + p0;

    if (tid < 128) lgs[tid] = lng[tid];
    else if (tid < 256) lbs[tid - 128] = lnb[tid - 128];

    // ---- ph1: stage Y tile [128 c][64 p] ----
    if constexpr (YBF) {
#pragma unroll
        for (int it = 0; it < 2; ++it) {
            const int row0 = it * 64 + wv * 8;
            const YT* gsrc = yp + (size_t)(row0 + (lane >> 3)) * PIMG + (lane & 7) * 8;
            __builtin_amdgcn_global_load_lds((const unsigned int*)gsrc,
                                             (unsigned int*)&yraw_b[row0][0], 16, 0, 0);
        }
    } else {
#pragma unroll
        for (int it = 0; it < 4; ++it) {
            const int c = it * 32 + (tid >> 4);
            const int ch = (tid & 15) * 4;
            *(f32x4*)&yraw_f[c][ch] = *(const f32x4*)(yp + (size_t)c * PIMG + ch);
        }
    }
    __syncthreads();

    auto ldy = [&](int c, int p) -> float {
        if constexpr (YBF) return (float)__builtin_bit_cast(__bf16, yraw_b[c][p]);
        else return yraw_f[c][p];
    };

    // ---- ph2: LN partials in f32 (validated r15; combine stays f64) ----
    {
        float s = 0.f, s2 = 0.f;
#pragma unroll
        for (int i = 0; i < 16; ++i) {
            const float v = ldy(wv * 16 + i, lane);
            s += v;
            s2 = fmaf(v, v, s2);
        }
        pls[wv][lane] = s;
        pls2[wv][lane] = s2;
    }
    __syncthreads();

    // ---- ph3: combine partials in f64 (proven formula) ----
    if (tid < 64) {
        const int p = tid;
        double s = 0.0, s2 = 0.0;
#pragma unroll
        for (int w = 0; w < 8; ++w) { s += (double)pls[w][p]; s2 += (double)pls2[w][p]; }
        const double mu = s * (1.0 / 128.0);
        const double var = (s2 - s * s * (1.0 / 128.0)) * (1.0 / 128.0);
        mud[p] = mu;
        rsd[p] = 1.0 / sqrt(var + 1e-5);
    }
    __syncthreads();

    // ---- ph4: normalize (f64, proven) + transpose-pack bf16 to yb[p][c], b64 writes ----
    {
        const int pos = tid & 63;
        const int cbase = (tid >> 6) * 16;   // 8 waves x 16 channels
        const double mu = mud[pos], rs = rsd[pos];
#pragma unroll
        for (int j = 0; j < 16; j += 4) {
            const int c = cbase + j;
            unsigned int pk[2];
#pragma unroll
            for (int q = 0; q < 2; ++q) {
                const int cc = c + 2 * q;
                const float v0 = (float)(((double)ldy(cc, pos) - mu) * rs) * lgs[cc] + lbs[cc];
                const float v1 = (float)(((double)ldy(cc + 1, pos) - mu) * rs) * lgs[cc + 1] + lbs[cc + 1];
                pk[q] = (unsigned int)__builtin_bit_cast(unsigned short, (__bf16)v0) |
                        ((unsigned int)__builtin_bit_cast(unsigned short, (__bf16)v1) << 16);
            }
            *(unsigned long long*)&yb[pos][c] =
                (unsigned long long)pk[0] | ((unsigned long long)pk[1] << 32);
        }
    }
    __syncthreads();

    const int l15 = lane & 15, l4 = lane >> 4;

    // GEMM1 one pass: wave owns 16 hid rows [hbase, hbase+16); acc1[4] = 16 AGPR
    f32x4 acc1[4];
    auto gemm1_pass = [&](int hbase) {
#pragma unroll
        for (int ct = 0; ct < 4; ++ct) acc1[ct] = (f32x4){0.f, 0.f, 0.f, 0.f};
        const __bf16* w1p = w1b + (size_t)hbase * 128;
#pragma unroll
        for (int k0 = 0; k0 < 128; k0 += 32) {
            bf16x8 bh[4];
#pragma unroll
            for (int ct = 0; ct < 4; ++ct)
                bh[ct] = *(const bf16x8*)&yb[ct * 16 + l15][k0 + l4 * 8];
            bf16x8 ah = *(const bf16x8*)(w1p + (size_t)l15 * 128 + k0 + l4 * 8);
#pragma unroll
            for (int ct = 0; ct < 4; ++ct)
                acc1[ct] = __builtin_amdgcn_mfma_f32_16x16x32_bf16(ah, bh[ct], acc1[ct], 0, 0, 0);
        }
    };

    // GELU + store 16 hid rows into chunk at column base
    auto gelu_store = [&](int hbase, int colbase) {
        const int hid0 = hbase + l4 * 4;
        const int col0 = colbase + l4 * 4;
        const float bb0 = b1[hid0], bb1 = b1[hid0 + 1];
        const float bb2v = b1[hid0 + 2], bb3 = b1[hid0 + 3];
#pragma unroll
        for (int ct = 0; ct < 4; ++ct) {
            const int p = ct * 16 + l15;
            float hv[4];
            hv[0] = gelu_tanh(acc1[ct][0] + bb0);
            hv[1] = gelu_tanh(acc1[ct][1] + bb1);
            hv[2] = gelu_tanh(acc1[ct][2] + bb2v);
            hv[3] = gelu_tanh(acc1[ct][3] + bb3);
            unsigned int lo = (unsigned int)__builtin_bit_cast(unsigned short, (__bf16)hv[0]) |
                              ((unsigned int)__builtin_bit_cast(unsigned short, (__bf16)hv[1]) << 16);
            unsigned int hi = (unsigned int)__builtin_bit_cast(unsigned short, (__bf16)hv[2]) |
                              ((unsigned int)__builtin_bit_cast(unsigned short, (__bf16)hv[3]) << 16);
            *(unsigned long long*)&hl[p][col0] =
                (unsigned long long)lo | ((unsigned long long)hi << 32);
        }
    };

    // ---- ph5: GEMM1 passes 0,1 (hid 0-255) -> chunk0 ----
    gemm1_pass(wv * 16);            gelu_store(wv * 16, wv * 16);
    gemm1_pass(128 + wv * 16);      gelu_store(128 + wv * 16, 128 + wv * 16);
    __syncthreads();                // acc1 dead on ALL waves

    f32x4 acc2[4];
#pragma unroll
    for (int ct = 0; ct < 4; ++ct) acc2[ct] = (f32x4){0.f, 0.f, 0.f, 0.f};
    const __bf16* w2p = w2b + (size_t)(wv * 16) * 512;

    // ---- ph6: GEMM2 phase 1, k = [0,256) ascending ----
#pragma unroll
    for (int k0 = 0; k0 < 256; k0 += 32) {
        bf16x8 bh[4];
#pragma unroll
        for (int ct = 0; ct < 4; ++ct)
            bh[ct] = *(const bf16x8*)&hl[ct * 16 + l15][k0 + l4 * 8];
        bf16x8 ah = *(const bf16x8*)(w2p + (size_t)l15 * 512 + k0 + l4 * 8);
#pragma unroll
        for (int ct = 0; ct < 4; ++ct)
            acc2[ct] = __builtin_amdgcn_mfma_f32_16x16x32_bf16(ah, bh[ct], acc2[ct], 0, 0, 0);
    }
    __syncthreads();  // phase-1 chunk reads done

    // ---- ph7: GEMM1 passes 2,3 (hid 256-511) -> chunk1 (acc2 live: 16+16 AGPR) ----
    gemm1_pass(256 + wv * 16);      gelu_store(256 + wv * 16, wv * 16);
    gemm1_pass(384 + wv * 16);      gelu_store(384 + wv * 16, 128 + wv * 16);
    __syncthreads();

    // ---- ph8: GEMM2 phase 2, k = [256,512) ascending ----
#pragma unroll
    for (int k0 = 256; k0 < 512; k0 += 32) {
        bf16x8 bh[4];
#pragma unroll
        for (int ct = 0; ct < 4; ++ct)
            bh[ct] = *(const bf16x8*)&hl[ct * 16 + l15][(k0 - 256) + l4 * 8];
        bf16x8 ah = *(const bf16x8*)(w2p + (size_t)l15 * 512 + k0 + l4 * 8);
#pragma unroll
        for (int ct = 0; ct < 4; ++ct)
            acc2[ct] = __builtin_amdgcn_mfma_f32_16x16x32_bf16(ah, bh[ct], acc2[ct], 0, 0, 0);
    }

    // ---- epilogue: + b2, * LayerScale, store [b][c][p] ----
    float* op = out + (size_t)b * ((size_t)C_ * PIMG) + p0;
    {
        const int c0 = wv * 16 + l4 * 4;
        float bv[4], lv[4];
#pragma unroll
        for (int r = 0; r < 4; ++r) { bv[r] = b2[c0 + r]; lv[r] = ls[c0 + r]; }
#pragma unroll
        for (int ct = 0; ct < 4; ++ct) {
            const int p = ct * 16 + l15;
#pragma unroll
            for (int r = 0; r < 4; ++r)
                op[(size_t)(c0 + r) * PIMG + p] = (acc2[ct][r] + bv[r]) * lv[r];
        }
    }
}

extern "C" void kernel_launch(void* const* d_in, const int* in_sizes, int n_in,
                              void* d_out, int out_size, void* d_ws, size_t ws_size,
                              hipStream_t stream) {
    const float* x   = (const float*)d_in[0];
    const float* dww = (const float*)d_in[1];
    const float* dwb = (const float*)d_in[2];
    const float* lng = (const float*)d_in[3];
    const float* lnb = (const float*)d_in[4];
    const float* w1  = (const float*)d_in[5];
    const float* b1  = (const float*)d_in[6];
    const float* w2  = (const float*)d_in[7];
    const float* b2  = (const float*)d_in[8];
    const float* ls  = (const float*)d_in[9];
    float* out = (float*)d_out;

    __bf16* w1b = (__bf16*)d_ws;
    __bf16* w2b = w1b + 65536;
    wcvt_k<<<65536 / 256, 256, 0, stream>>>(w1, w2, w1b, w2b);

    const size_t interElems = (size_t)B_ * C_ * PIMG;           // 33.5M
    const size_t needWs = 262144 + interElems * 2;              // weights + bf16 y
    if (ws_size >= needWs) {
        __bf16* yc = (__bf16*)((char*)d_ws + 262144);
        dwconv_k<__bf16><<<B_ * C_ * (T_ / 32), 256, 0, stream>>>(x, dww, dwb, yc);
        lnmlp_k<__bf16><<<B_ * (PIMG / 64), 512, 0, stream>>>(yc, w1b, w2b,
                                                              lng, lnb, b1, b2, ls, out);
    } else {
        // fallback: fp32 y aliasing d_out (proven race-free: identical addressing,
        // each block reads exactly the region it later writes)
        float* yc = out;
        dwconv_k<float><<<B_ * C_ * (T_ / 32), 256, 0, stream>>>(x, dww, dwb, yc);
        lnmlp_k<float><<<B_ * (PIMG / 64), 512, 0, stream>>>(yc, w1b, w2b,
                                                             lng, lnb, b1, b2, ls, out);
    }
}

// Round 17
// 254.761 us; speedup vs baseline: 1.2616x; 1.2616x over previous
//
#include <hip/hip_runtime.h>
#include <hip/hip_bf16.h>
#include <math.h>

typedef __bf16 bf16x8 __attribute__((ext_vector_type(8)));
typedef float f32x4 __attribute__((ext_vector_type(4)));

constexpr int C_ = 128, HID_ = 512, T_ = 512, F_ = 128, B_ = 4;
constexpr int PIMG = T_ * F_;  // 65536 positions per image

// ---------------- Kernel 0: weight fp32 -> bf16 ----------------
__global__ void wcvt_k(const float* __restrict__ w1, const float* __restrict__ w2,
                       __bf16* __restrict__ w1b, __bf16* __restrict__ w2b) {
    int i = blockIdx.x * 256 + threadIdx.x;   // 65536 each
    w1b[i] = (__bf16)w1[i];
    w2b[i] = (__bf16)w2[i];
}

// ---------------- Kernel A: depthwise 7x7 conv, 16B-ALIGNED LDS tile ----------------
// KNOWN GOOD structure (round 6); templated output type. ~35 us (traffic floor ~32).
template <typename OT>
__global__ __launch_bounds__(256) void dwconv_k(
    const float* __restrict__ x, const float* __restrict__ dww,
    const float* __restrict__ dwb, OT* __restrict__ y) {
    __shared__ float tile[38][140];  // rows t0-3..t0+34; 21280 B
    const int bx = blockIdx.x;
    const int tt = bx & 15, c = (bx >> 4) & 127, b = bx >> 11;
    const int t0 = tt * 32;
    const float* xp = x + ((size_t)(b * C_ + c)) * PIMG;

    float wr[49];  // uniform per block -> scalarized
#pragma unroll
    for (int i = 0; i < 49; ++i) wr[i] = dww[c * 49 + i];
    const float bias = dwb[c];

    const int colq = threadIdx.x & 31;
    const int rg = threadIdx.x >> 5;
    for (int r = rg; r < 38; r += 8) {
        const int t = t0 - 3 + r;
        f32x4 v = {0.f, 0.f, 0.f, 0.f};
        if (t >= 0 && t < T_) v = *(const f32x4*)(xp + (size_t)t * F_ + colq * 4);
        *(f32x4*)&tile[r][4 + colq * 4] = v;   // 16B-aligned
        if (colq == 0) { tile[r][1] = 0.f; tile[r][2] = 0.f; tile[r][3] = 0.f; }
        if (colq == 31) { tile[r][132] = 0.f; tile[r][133] = 0.f; tile[r][134] = 0.f; }
    }
    __syncthreads();

    const int f = threadIdx.x & 127;
    const int g = threadIdx.x >> 7;  // 0..1 -> 16 t-rows each
    float acc[16];
#pragma unroll
    for (int i = 0; i < 16; ++i) acc[i] = 0.f;
#pragma unroll
    for (int df = 0; df < 7; ++df) {
        float colv[22];  // sliding window: 22 loads feed 112 FMAs
#pragma unroll
        for (int j = 0; j < 22; ++j) colv[j] = tile[g * 16 + j][1 + f + df];
#pragma unroll
        for (int dr = 0; dr < 7; ++dr) {
            const float wv = wr[dr * 7 + df];
#pragma unroll
            for (int i = 0; i < 16; ++i) acc[i] += colv[i + dr] * wv;
        }
    }
    OT* yp = y + ((size_t)(b * C_ + c)) * PIMG + (size_t)(t0 + g * 16) * F_ + f;
#pragma unroll
    for (int i = 0; i < 16; ++i) yp[(size_t)i * F_] = (OT)(acc[i] + bias);
}

// gelu = 0.5x(1+tanh(u)) == x / (1 + exp(-2u))  [exact rewrite, validated r12-r16]
__device__ __forceinline__ float gelu_tanh(float xv) {
    const float u2 = 1.5957691216057308f * (xv + 0.044715f * xv * xv * xv);  // 2u
    const float e = __expf(-u2);
    return __fdividef(xv, 1.f + e);
}

// ---------------- Kernel B: r15 structure (proven best) + merged LN combine ----------------
// grid: B * (PIMG/64) = 4096 blocks, 512 threads (8 waves), 2 blocks/CU.
// Occupancy axis CLOSED (r12/r16): true footprint ~96 regs (48V+48A); any
// launch_bounds cap below that spills (r16: 552 MB scratch writes). (512,4) it is.
// Change vs r15: ph3 (64-thread serial combine + barrier) merged into ph4 —
// every thread redundantly combines its position's partials in the SAME f64
// order => bit-identical mu/rs, one fewer barrier, no 448-thread idle phase.
// Fallback (YT=float): y may alias out — disjoint regions, reads before writes.
template <typename YT>
__global__ __launch_bounds__(512, 4) void lnmlp_k(
    const YT* y,
    const __bf16* __restrict__ w1b, const __bf16* __restrict__ w2b,
    const float* __restrict__ lng, const float* __restrict__ lnb,
    const float* __restrict__ b1, const float* __restrict__ b2,
    const float* __restrict__ ls, float* out) {
    constexpr bool YBF = (sizeof(YT) == 2);
    constexpr int YB_BYTES = 17408;                       // yb [64][136] bf16
    constexpr int YRAW_BYTES = YBF ? 16384 : 34816;       // [128][64]bf16 | [128][68]f32
    constexpr int FRESH_OFF = YB_BYTES + YRAW_BYTES;      // statics region (5 KB)
    constexpr int CHUNK_END = YB_BYTES + 33792;           // hl [64][264] end
    constexpr int A_ = FRESH_OFF + 5120;
    constexpr int SMEM_SZ = (A_ > CHUNK_END) ? A_ : CHUNK_END;  // ~51 KB bf16
    __shared__ __align__(16) unsigned char smem[SMEM_SZ];
    unsigned short (*yb)[136] = (unsigned short (*)[136])smem;
    unsigned short (*yraw_b)[64] = (unsigned short (*)[64])(smem + YB_BYTES);
    float (*yraw_f)[68] = (float (*)[68])(smem + YB_BYTES);
    unsigned short (*hl)[264] = (unsigned short (*)[264])(smem + YB_BYTES);  // overlays yraw+statics
    float (*pls)[64] = (float (*)[64])(smem + FRESH_OFF);          // live ph2-4 only
    float (*pls2)[64] = (float (*)[64])(smem + FRESH_OFF + 2048);
    float* lgs = (float*)(smem + FRESH_OFF + 4096);                // live ph0-4
    float* lbs = (float*)(smem + FRESH_OFF + 4608);

    const int tid = threadIdx.x;
    const int lane = tid & 63, wv = tid >> 6;
    const int b = blockIdx.x >> 10;
    const int p0 = (blockIdx.x & 1023) * 64;
    const YT* yp = y + (size_t)b * ((size_t)C_ * PIMG) + p0;

    if (tid < 128) lgs[tid] = lng[tid];
    else if (tid < 256) lbs[tid - 128] = lnb[tid - 128];

    // ---- ph1: stage Y tile [128 c][64 p] ----
    if constexpr (YBF) {
#pragma unroll
        for (int it = 0; it < 2; ++it) {
            const int row0 = it * 64 + wv * 8;
            const YT* gsrc = yp + (size_t)(row0 + (lane >> 3)) * PIMG + (lane & 7) * 8;
            __builtin_amdgcn_global_load_lds((const unsigned int*)gsrc,
                                             (unsigned int*)&yraw_b[row0][0], 16, 0, 0);
        }
    } else {
#pragma unroll
        for (int it = 0; it < 4; ++it) {
            const int c = it * 32 + (tid >> 4);
            const int ch = (tid & 15) * 4;
            *(f32x4*)&yraw_f[c][ch] = *(const f32x4*)(yp + (size_t)c * PIMG + ch);
        }
    }
    __syncthreads();

    auto ldy = [&](int c, int p) -> float {
        if constexpr (YBF) return (float)__builtin_bit_cast(__bf16, yraw_b[c][p]);
        else return yraw_f[c][p];
    };

    // ---- ph2: LN partials in f32 (validated r15) ----
    {
        float s = 0.f, s2 = 0.f;
#pragma unroll
        for (int i = 0; i < 16; ++i) {
            const float v = ldy(wv * 16 + i, lane);
            s += v;
            s2 = fmaf(v, v, s2);
        }
        pls[wv][lane] = s;
        pls2[wv][lane] = s2;
    }
    __syncthreads();

    // ---- ph3+ph4 merged: per-thread f64 combine (redundant, bit-identical) +
    //      normalize (f64, proven) + transpose-pack bf16 to yb[p][c] ----
    {
        const int pos = tid & 63;
        double s = 0.0, s2 = 0.0;
#pragma unroll
        for (int w = 0; w < 8; ++w) { s += (double)pls[w][pos]; s2 += (double)pls2[w][pos]; }
        const double mu = s * (1.0 / 128.0);
        const double var = (s2 - s * s * (1.0 / 128.0)) * (1.0 / 128.0);
        const double rs = 1.0 / sqrt(var + 1e-5);
        const int cbase = (tid >> 6) * 16;   // 8 waves x 16 channels
#pragma unroll
        for (int j = 0; j < 16; j += 4) {
            const int c = cbase + j;
            unsigned int pk[2];
#pragma unroll
            for (int q = 0; q < 2; ++q) {
                const int cc = c + 2 * q;
                const float v0 = (float)(((double)ldy(cc, pos) - mu) * rs) * lgs[cc] + lbs[cc];
                const float v1 = (float)(((double)ldy(cc + 1, pos) - mu) * rs) * lgs[cc + 1] + lbs[cc + 1];
                pk[q] = (unsigned int)__builtin_bit_cast(unsigned short, (__bf16)v0) |
                        ((unsigned int)__builtin_bit_cast(unsigned short, (__bf16)v1) << 16);
            }
            *(unsigned long long*)&yb[pos][c] =
                (unsigned long long)pk[0] | ((unsigned long long)pk[1] << 32);
        }
    }
    __syncthreads();

    const int l15 = lane & 15, l4 = lane >> 4;

    // GEMM1 one pass: wave owns 32 hid rows [hbase, hbase+32); acc1[2][4] = 32 AGPR
    f32x4 acc1[2][4];
    auto gemm1_pass = [&](int hbase) {
#pragma unroll
        for (int m = 0; m < 2; ++m)
#pragma unroll
            for (int ct = 0; ct < 4; ++ct) acc1[m][ct] = (f32x4){0.f, 0.f, 0.f, 0.f};
        const __bf16* w1p = w1b + (size_t)hbase * 128;
#pragma unroll
        for (int k0 = 0; k0 < 128; k0 += 32) {
            bf16x8 bh[4];
#pragma unroll
            for (int ct = 0; ct < 4; ++ct)
                bh[ct] = *(const bf16x8*)&yb[ct * 16 + l15][k0 + l4 * 8];
#pragma unroll
            for (int m = 0; m < 2; ++m) {
                bf16x8 ah = *(const bf16x8*)(w1p + (size_t)(m * 16 + l15) * 128 + k0 + l4 * 8);
#pragma unroll
                for (int ct = 0; ct < 4; ++ct)
                    acc1[m][ct] = __builtin_amdgcn_mfma_f32_16x16x32_bf16(ah, bh[ct], acc1[m][ct], 0, 0, 0);
            }
        }
    };

    // GELU + store: chunk col = hid - chunk_base (chunk holds 256 hid)
    auto gelu_store = [&](int hbase, int cbase2) {
#pragma unroll
        for (int m = 0; m < 2; ++m) {
            const int hid0 = hbase + m * 16 + l4 * 4;
            const int col0 = cbase2 + m * 16 + l4 * 4;
            const float bb0 = b1[hid0], bb1 = b1[hid0 + 1];
            const float bb2v = b1[hid0 + 2], bb3 = b1[hid0 + 3];
#pragma unroll
            for (int ct = 0; ct < 4; ++ct) {
                const int p = ct * 16 + l15;
                float hv[4];
                hv[0] = gelu_tanh(acc1[m][ct][0] + bb0);
                hv[1] = gelu_tanh(acc1[m][ct][1] + bb1);
                hv[2] = gelu_tanh(acc1[m][ct][2] + bb2v);
                hv[3] = gelu_tanh(acc1[m][ct][3] + bb3);
                unsigned int lo = (unsigned int)__builtin_bit_cast(unsigned short, (__bf16)hv[0]) |
                                  ((unsigned int)__builtin_bit_cast(unsigned short, (__bf16)hv[1]) << 16);
                unsigned int hi = (unsigned int)__builtin_bit_cast(unsigned short, (__bf16)hv[2]) |
                                  ((unsigned int)__builtin_bit_cast(unsigned short, (__bf16)hv[3]) << 16);
                *(unsigned long long*)&hl[p][col0] =
                    (unsigned long long)lo | ((unsigned long long)hi << 32);
            }
        }
    };

    // ---- ph5: GEMM1 pass A (hid 0-255: wave wv -> [32wv,32wv+32)) + store chunk0 ----
    gemm1_pass(wv * 32);
    gelu_store(wv * 32, wv * 32);   // chunk0: col == hid
    __syncthreads();                // acc1 dead on ALL waves here

    f32x4 acc2[4];
#pragma unroll
    for (int ct = 0; ct < 4; ++ct) acc2[ct] = (f32x4){0.f, 0.f, 0.f, 0.f};
    const __bf16* w2p = w2b + (size_t)(wv * 16) * 512;

    // ---- ph6: GEMM2 phase 1, k = [0,256) ascending ----
#pragma unroll
    for (int k0 = 0; k0 < 256; k0 += 32) {
        bf16x8 bh[4];
#pragma unroll
        for (int ct = 0; ct < 4; ++ct)
            bh[ct] = *(const bf16x8*)&hl[ct * 16 + l15][k0 + l4 * 8];
        bf16x8 ah = *(const bf16x8*)(w2p + (size_t)l15 * 512 + k0 + l4 * 8);
#pragma unroll
        for (int ct = 0; ct < 4; ++ct)
            acc2[ct] = __builtin_amdgcn_mfma_f32_16x16x32_bf16(ah, bh[ct], acc2[ct], 0, 0, 0);
    }
    __syncthreads();  // phase-1 chunk reads done

    // ---- ph7: GEMM1 pass B (hid 256-511) + store chunk1 (yb still live) ----
    gemm1_pass(256 + wv * 32);
    gelu_store(256 + wv * 32, wv * 32);   // chunk1: col == hid - 256
    __syncthreads();

    // ---- ph8: GEMM2 phase 2, k = [256,512) ascending ----
#pragma unroll
    for (int k0 = 256; k0 < 512; k0 += 32) {
        bf16x8 bh[4];
#pragma unroll
        for (int ct = 0; ct < 4; ++ct)
            bh[ct] = *(const bf16x8*)&hl[ct * 16 + l15][(k0 - 256) + l4 * 8];
        bf16x8 ah = *(const bf16x8*)(w2p + (size_t)l15 * 512 + k0 + l4 * 8);
#pragma unroll
        for (int ct = 0; ct < 4; ++ct)
            acc2[ct] = __builtin_amdgcn_mfma_f32_16x16x32_bf16(ah, bh[ct], acc2[ct], 0, 0, 0);
    }

    // ---- epilogue: + b2, * LayerScale, store [b][c][p] ----
    float* op = out + (size_t)b * ((size_t)C_ * PIMG) + p0;
    {
        const int c0 = wv * 16 + l4 * 4;
        float bv[4], lv[4];
#pragma unroll
        for (int r = 0; r < 4; ++r) { bv[r] = b2[c0 + r]; lv[r] = ls[c0 + r]; }
#pragma unroll
        for (int ct = 0; ct < 4; ++ct) {
            const int p = ct * 16 + l15;
#pragma unroll
            for (int r = 0; r < 4; ++r)
                op[(size_t)(c0 + r) * PIMG + p] = (acc2[ct][r] + bv[r]) * lv[r];
        }
    }
}

extern "C" void kernel_launch(void* const* d_in, const int* in_sizes, int n_in,
                              void* d_out, int out_size, void* d_ws, size_t ws_size,
                              hipStream_t stream) {
    const float* x   = (const float*)d_in[0];
    const float* dww = (const float*)d_in[1];
    const float* dwb = (const float*)d_in[2];
    const float* lng = (const float*)d_in[3];
    const float* lnb = (const float*)d_in[4];
    const float* w1  = (const float*)d_in[5];
    const float* b1  = (const float*)d_in[6];
    const float* w2  = (const float*)d_in[7];
    const float* b2  = (const float*)d_in[8];
    const float* ls  = (const float*)d_in[9];
    float* out = (float*)d_out;

    __bf16* w1b = (__bf16*)d_ws;
    __bf16* w2b = w1b + 65536;
    wcvt_k<<<65536 / 256, 256, 0, stream>>>(w1, w2, w1b, w2b);

    const size_t interElems = (size_t)B_ * C_ * PIMG;           // 33.5M
    const size_t needWs = 262144 + interElems * 2;              // weights + bf16 y
    if (ws_size >= needWs) {
        __bf16* yc = (__bf16*)((char*)d_ws + 262144);
        dwconv_k<__bf16><<<B_ * C_ * (T_ / 32), 256, 0, stream>>>(x, dww, dwb, yc);
        lnmlp_k<__bf16><<<B_ * (PIMG / 64), 512, 0, stream>>>(yc, w1b, w2b,
                                                              lng, lnb, b1, b2, ls, out);
    } else {
        // fallback: fp32 y aliasing d_out (proven race-free: identical addressing,
        // each block reads exactly the region it later writes)
        float* yc = out;
        dwconv_k<float><<<B_ * C_ * (T_ / 32), 256, 0, stream>>>(x, dww, dwb, yc);
        lnmlp_k<float><<<B_ * (PIMG / 64), 512, 0, stream>>>(yc, w1b, w2b,
                                                             lng, lnb, b1, b2, ls, out);
    }
}

// Round 18
// 248.878 us; speedup vs baseline: 1.2914x; 1.0236x over previous
//
#include <hip/hip_runtime.h>
#include <hip/hip_bf16.h>
#include <math.h>

typedef __bf16 bf16x8 __attribute__((ext_vector_type(8)));
typedef float f32x4 __attribute__((ext_vector_type(4)));

constexpr int C_ = 128, HID_ = 512, T_ = 512, F_ = 128, B_ = 4;
constexpr int PIMG = T_ * F_;  // 65536 positions per image

// ---------------- Kernel A: wcvt (blocks 0-255) + depthwise 7x7 conv ----------------
// Conv part KNOWN GOOD (round 6): 16B-aligned LDS tile. wcvt blocks convert
// weights and return before any barrier (uniform per-block branch).
template <typename OT>
__global__ __launch_bounds__(256) void dwconv_k(
    const float* __restrict__ x, const float* __restrict__ dww,
    const float* __restrict__ dwb, OT* __restrict__ y,
    const float* __restrict__ w1, const float* __restrict__ w2,
    __bf16* __restrict__ w1b, __bf16* __restrict__ w2b) {
    __shared__ float tile[38][140];  // rows t0-3..t0+34; 21280 B
    const int bxr = blockIdx.x;
    if (bxr < 256) {   // weight conversion: 256 blocks x 256 threads = 65536
        const int i = bxr * 256 + threadIdx.x;
        w1b[i] = (__bf16)w1[i];
        w2b[i] = (__bf16)w2[i];
        return;
    }
    const int bx = bxr - 256;
    const int tt = bx & 15, c = (bx >> 4) & 127, b = bx >> 11;
    const int t0 = tt * 32;
    const float* xp = x + ((size_t)(b * C_ + c)) * PIMG;

    float wr[49];  // uniform per block -> scalarized
#pragma unroll
    for (int i = 0; i < 49; ++i) wr[i] = dww[c * 49 + i];
    const float bias = dwb[c];

    const int colq = threadIdx.x & 31;
    const int rg = threadIdx.x >> 5;
    for (int r = rg; r < 38; r += 8) {
        const int t = t0 - 3 + r;
        f32x4 v = {0.f, 0.f, 0.f, 0.f};
        if (t >= 0 && t < T_) v = *(const f32x4*)(xp + (size_t)t * F_ + colq * 4);
        *(f32x4*)&tile[r][4 + colq * 4] = v;   // 16B-aligned
        if (colq == 0) { tile[r][1] = 0.f; tile[r][2] = 0.f; tile[r][3] = 0.f; }
        if (colq == 31) { tile[r][132] = 0.f; tile[r][133] = 0.f; tile[r][134] = 0.f; }
    }
    __syncthreads();

    const int f = threadIdx.x & 127;
    const int g = threadIdx.x >> 7;  // 0..1 -> 16 t-rows each
    float acc[16];
#pragma unroll
    for (int i = 0; i < 16; ++i) acc[i] = 0.f;
#pragma unroll
    for (int df = 0; df < 7; ++df) {
        float colv[22];  // sliding window: 22 loads feed 112 FMAs
#pragma unroll
        for (int j = 0; j < 22; ++j) colv[j] = tile[g * 16 + j][1 + f + df];
#pragma unroll
        for (int dr = 0; dr < 7; ++dr) {
            const float wv = wr[dr * 7 + df];
#pragma unroll
            for (int i = 0; i < 16; ++i) acc[i] += colv[i + dr] * wv;
        }
    }
    OT* yp = y + ((size_t)(b * C_ + c)) * PIMG + (size_t)(t0 + g * 16) * F_ + f;
#pragma unroll
    for (int i = 0; i < 16; ++i) yp[(size_t)i * F_] = (OT)(acc[i] + bias);
}

// gelu = 0.5x(1+tanh(u)) == x / (1 + exp(-2u))  [exact rewrite, validated r12-r17]
__device__ __forceinline__ float gelu_tanh(float xv) {
    const float u2 = 1.5957691216057308f * (xv + 0.044715f * xv * xv * xv);  // 2u
    const float e = __expf(-u2);
    return __fdividef(xv, 1.f + e);
}

// ---------------- Kernel B: UNCHANGED from round 17 (proven best, bit-stable) ----------------
// grid: B * (PIMG/64) = 4096 blocks, 512 threads (8 waves), 2 blocks/CU.
// Occupancy axis CLOSED (r12/r16): true footprint ~96 regs; caps below spill.
// LDS b128 bank pattern analyzed: uniform-8 start distribution = structural floor
// (swizzle provably cannot improve it — 16B-aligned starts admit 8 banks only).
// Fallback (YT=float): y may alias out — disjoint regions, reads before writes.
template <typename YT>
__global__ __launch_bounds__(512, 4) void lnmlp_k(
    const YT* y,
    const __bf16* __restrict__ w1b, const __bf16* __restrict__ w2b,
    const float* __restrict__ lng, const float* __restrict__ lnb,
    const float* __restrict__ b1, const float* __restrict__ b2,
    const float* __restrict__ ls, float* out) {
    constexpr bool YBF = (sizeof(YT) == 2);
    constexpr int YB_BYTES = 17408;                       // yb [64][136] bf16
    constexpr int YRAW_BYTES = YBF ? 16384 : 34816;       // [128][64]bf16 | [128][68]f32
    constexpr int FRESH_OFF = YB_BYTES + YRAW_BYTES;      // statics region (5 KB)
    constexpr int CHUNK_END = YB_BYTES + 33792;           // hl [64][264] end
    constexpr int A_ = FRESH_OFF + 5120;
    constexpr int SMEM_SZ = (A_ > CHUNK_END) ? A_ : CHUNK_END;  // ~51 KB bf16
    __shared__ __align__(16) unsigned char smem[SMEM_SZ];
    unsigned short (*yb)[136] = (unsigned short (*)[136])smem;
    unsigned short (*yraw_b)[64] = (unsigned short (*)[64])(smem + YB_BYTES);
    float (*yraw_f)[68] = (float (*)[68])(smem + YB_BYTES);
    unsigned short (*hl)[264] = (unsigned short (*)[264])(smem + YB_BYTES);  // overlays yraw+statics
    float (*pls)[64] = (float (*)[64])(smem + FRESH_OFF);          // live ph2-4 only
    float (*pls2)[64] = (float (*)[64])(smem + FRESH_OFF + 2048);
    float* lgs = (float*)(smem + FRESH_OFF + 4096);                // live ph0-4
    float* lbs = (float*)(smem + FRESH_OFF + 4608);

    const int tid = threadIdx.x;
    const int lane = tid & 63, wv = tid >> 6;
    const int b = blockIdx.x >> 10;
    const int p0 = (blockIdx.x & 1023) * 64;
    const YT* yp = y + (size_t)b * ((size_t)C_ * PIMG) + p0;

    if (tid < 128) lgs[tid] = lng[tid];
    else if (tid < 256) lbs[tid - 128] = lnb[tid - 128];

    // ---- ph1: stage Y tile [128 c][64 p] ----
    if constexpr (YBF) {
#pragma unroll
        for (int it = 0; it < 2; ++it) {
            const int row0 = it * 64 + wv * 8;
            const YT* gsrc = yp + (size_t)(row0 + (lane >> 3)) * PIMG + (lane & 7) * 8;
            __builtin_amdgcn_global_load_lds((const unsigned int*)gsrc,
                                             (unsigned int*)&yraw_b[row0][0], 16, 0, 0);
        }
    } else {
#pragma unroll
        for (int it = 0; it < 4; ++it) {
            const int c = it * 32 + (tid >> 4);
            const int ch = (tid & 15) * 4;
            *(f32x4*)&yraw_f[c][ch] = *(const f32x4*)(yp + (size_t)c * PIMG + ch);
        }
    }
    __syncthreads();

    auto ldy = [&](int c, int p) -> float {
        if constexpr (YBF) return (float)__builtin_bit_cast(__bf16, yraw_b[c][p]);
        else return yraw_f[c][p];
    };

    // ---- ph2: LN partials in f32 (validated r15) ----
    {
        float s = 0.f, s2 = 0.f;
#pragma unroll
        for (int i = 0; i < 16; ++i) {
            const float v = ldy(wv * 16 + i, lane);
            s += v;
            s2 = fmaf(v, v, s2);
        }
        pls[wv][lane] = s;
        pls2[wv][lane] = s2;
    }
    __syncthreads();

    // ---- ph3+ph4: per-thread f64 combine (bit-identical order) + normalize + pack ----
    {
        const int pos = tid & 63;
        double s = 0.0, s2 = 0.0;
#pragma unroll
        for (int w = 0; w < 8; ++w) { s += (double)pls[w][pos]; s2 += (double)pls2[w][pos]; }
        const double mu = s * (1.0 / 128.0);
        const double var = (s2 - s * s * (1.0 / 128.0)) * (1.0 / 128.0);
        const double rs = 1.0 / sqrt(var + 1e-5);
        const int cbase = (tid >> 6) * 16;   // 8 waves x 16 channels
#pragma unroll
        for (int j = 0; j < 16; j += 4) {
            const int c = cbase + j;
            unsigned int pk[2];
#pragma unroll
            for (int q = 0; q < 2; ++q) {
                const int cc = c + 2 * q;
                const float v0 = (float)(((double)ldy(cc, pos) - mu) * rs) * lgs[cc] + lbs[cc];
                const float v1 = (float)(((double)ldy(cc + 1, pos) - mu) * rs) * lgs[cc + 1] + lbs[cc + 1];
                pk[q] = (unsigned int)__builtin_bit_cast(unsigned short, (__bf16)v0) |
                        ((unsigned int)__builtin_bit_cast(unsigned short, (__bf16)v1) << 16);
            }
            *(unsigned long long*)&yb[pos][c] =
                (unsigned long long)pk[0] | ((unsigned long long)pk[1] << 32);
        }
    }
    __syncthreads();

    const int l15 = lane & 15, l4 = lane >> 4;

    // GEMM1 one pass: wave owns 32 hid rows [hbase, hbase+32); acc1[2][4] = 32 AGPR
    f32x4 acc1[2][4];
    auto gemm1_pass = [&](int hbase) {
#pragma unroll
        for (int m = 0; m < 2; ++m)
#pragma unroll
            for (int ct = 0; ct < 4; ++ct) acc1[m][ct] = (f32x4){0.f, 0.f, 0.f, 0.f};
        const __bf16* w1p = w1b + (size_t)hbase * 128;
#pragma unroll
        for (int k0 = 0; k0 < 128; k0 += 32) {
            bf16x8 bh[4];
#pragma unroll
            for (int ct = 0; ct < 4; ++ct)
                bh[ct] = *(const bf16x8*)&yb[ct * 16 + l15][k0 + l4 * 8];
#pragma unroll
            for (int m = 0; m < 2; ++m) {
                bf16x8 ah = *(const bf16x8*)(w1p + (size_t)(m * 16 + l15) * 128 + k0 + l4 * 8);
#pragma unroll
                for (int ct = 0; ct < 4; ++ct)
                    acc1[m][ct] = __builtin_amdgcn_mfma_f32_16x16x32_bf16(ah, bh[ct], acc1[m][ct], 0, 0, 0);
            }
        }
    };

    // GELU + store: chunk col = hid - chunk_base (chunk holds 256 hid)
    auto gelu_store = [&](int hbase, int cbase2) {
#pragma unroll
        for (int m = 0; m < 2; ++m) {
            const int hid0 = hbase + m * 16 + l4 * 4;
            const int col0 = cbase2 + m * 16 + l4 * 4;
            const float bb0 = b1[hid0], bb1 = b1[hid0 + 1];
            const float bb2v = b1[hid0 + 2], bb3 = b1[hid0 + 3];
#pragma unroll
            for (int ct = 0; ct < 4; ++ct) {
                const int p = ct * 16 + l15;
                float hv[4];
                hv[0] = gelu_tanh(acc1[m][ct][0] + bb0);
                hv[1] = gelu_tanh(acc1[m][ct][1] + bb1);
                hv[2] = gelu_tanh(acc1[m][ct][2] + bb2v);
                hv[3] = gelu_tanh(acc1[m][ct][3] + bb3);
                unsigned int lo = (unsigned int)__builtin_bit_cast(unsigned short, (__bf16)hv[0]) |
                                  ((unsigned int)__builtin_bit_cast(unsigned short, (__bf16)hv[1]) << 16);
                unsigned int hi = (unsigned int)__builtin_bit_cast(unsigned short, (__bf16)hv[2]) |
                                  ((unsigned int)__builtin_bit_cast(unsigned short, (__bf16)hv[3]) << 16);
                *(unsigned long long*)&hl[p][col0] =
                    (unsigned long long)lo | ((unsigned long long)hi << 32);
            }
        }
    };

    // ---- ph5: GEMM1 pass A (hid 0-255) + store chunk0 ----
    gemm1_pass(wv * 32);
    gelu_store(wv * 32, wv * 32);   // chunk0: col == hid
    __syncthreads();                // acc1 dead on ALL waves here

    f32x4 acc2[4];
#pragma unroll
    for (int ct = 0; ct < 4; ++ct) acc2[ct] = (f32x4){0.f, 0.f, 0.f, 0.f};
    const __bf16* w2p = w2b + (size_t)(wv * 16) * 512;

    // ---- ph6: GEMM2 phase 1, k = [0,256) ascending ----
#pragma unroll
    for (int k0 = 0; k0 < 256; k0 += 32) {
        bf16x8 bh[4];
#pragma unroll
        for (int ct = 0; ct < 4; ++ct)
            bh[ct] = *(const bf16x8*)&hl[ct * 16 + l15][k0 + l4 * 8];
        bf16x8 ah = *(const bf16x8*)(w2p + (size_t)l15 * 512 + k0 + l4 * 8);
#pragma unroll
        for (int ct = 0; ct < 4; ++ct)
            acc2[ct] = __builtin_amdgcn_mfma_f32_16x16x32_bf16(ah, bh[ct], acc2[ct], 0, 0, 0);
    }
    __syncthreads();  // phase-1 chunk reads done

    // ---- ph7: GEMM1 pass B (hid 256-511) + store chunk1 (yb still live) ----
    gemm1_pass(256 + wv * 32);
    gelu_store(256 + wv * 32, wv * 32);   // chunk1: col == hid - 256
    __syncthreads();

    // ---- ph8: GEMM2 phase 2, k = [256,512) ascending ----
#pragma unroll
    for (int k0 = 256; k0 < 512; k0 += 32) {
        bf16x8 bh[4];
#pragma unroll
        for (int ct = 0; ct < 4; ++ct)
            bh[ct] = *(const bf16x8*)&hl[ct * 16 + l15][(k0 - 256) + l4 * 8];
        bf16x8 ah = *(const bf16x8*)(w2p + (size_t)l15 * 512 + k0 + l4 * 8);
#pragma unroll
        for (int ct = 0; ct < 4; ++ct)
            acc2[ct] = __builtin_amdgcn_mfma_f32_16x16x32_bf16(ah, bh[ct], acc2[ct], 0, 0, 0);
    }

    // ---- epilogue: + b2, * LayerScale, store [b][c][p] ----
    float* op = out + (size_t)b * ((size_t)C_ * PIMG) + p0;
    {
        const int c0 = wv * 16 + l4 * 4;
        float bv[4], lv[4];
#pragma unroll
        for (int r = 0; r < 4; ++r) { bv[r] = b2[c0 + r]; lv[r] = ls[c0 + r]; }
#pragma unroll
        for (int ct = 0; ct < 4; ++ct) {
            const int p = ct * 16 + l15;
#pragma unroll
            for (int r = 0; r < 4; ++r)
                op[(size_t)(c0 + r) * PIMG + p] = (acc2[ct][r] + bv[r]) * lv[r];
        }
    }
}

extern "C" void kernel_launch(void* const* d_in, const int* in_sizes, int n_in,
                              void* d_out, int out_size, void* d_ws, size_t ws_size,
                              hipStream_t stream) {
    const float* x   = (const float*)d_in[0];
    const float* dww = (const float*)d_in[1];
    const float* dwb = (const float*)d_in[2];
    const float* lng = (const float*)d_in[3];
    const float* lnb = (const float*)d_in[4];
    const float* w1  = (const float*)d_in[5];
    const float* b1  = (const float*)d_in[6];
    const float* w2  = (const float*)d_in[7];
    const float* b2  = (const float*)d_in[8];
    const float* ls  = (const float*)d_in[9];
    float* out = (float*)d_out;

    __bf16* w1b = (__bf16*)d_ws;
    __bf16* w2b = w1b + 65536;

    const size_t interElems = (size_t)B_ * C_ * PIMG;           // 33.5M
    const size_t needWs = 262144 + interElems * 2;              // weights + bf16 y
    if (ws_size >= needWs) {
        __bf16* yc = (__bf16*)((char*)d_ws + 262144);
        dwconv_k<__bf16><<<256 + B_ * C_ * (T_ / 32), 256, 0, stream>>>(
            x, dww, dwb, yc, w1, w2, w1b, w2b);
        lnmlp_k<__bf16><<<B_ * (PIMG / 64), 512, 0, stream>>>(yc, w1b, w2b,
                                                              lng, lnb, b1, b2, ls, out);
    } else {
        // fallback: fp32 y aliasing d_out (proven race-free: identical addressing,
        // each block reads exactly the region it later writes)
        float* yc = out;
        dwconv_k<float><<<256 + B_ * C_ * (T_ / 32), 256, 0, stream>>>(
            x, dww, dwb, yc, w1, w2, w1b, w2b);
        lnmlp_k<float><<<B_ * (PIMG / 64), 512, 0, stream>>>(yc, w1b, w2b,
                                                             lng, lnb, b1, b2, ls, out);
    }
}